// Round 3
// baseline (1271.259 us; speedup 1.0000x reference)
//
#include <hip/hip_runtime.h>
#include <stdint.h>

typedef __bf16 bf16;
typedef bf16 bf16x8 __attribute__((ext_vector_type(8)));
typedef bf16 bf16x4 __attribute__((ext_vector_type(4)));
typedef float f32x4 __attribute__((ext_vector_type(4)));

#define BROWS 16384
#define BM 128
#define BK 64
#define SL ((size_t)BROWS * 256)

__device__ __forceinline__ float sigmoidf_(float x) { return 1.0f / (1.0f + __expf(-x)); }
__device__ __forceinline__ float tanhf_(float x)    { return 1.0f - 2.0f / (1.0f + __expf(2.0f * x)); }

__device__ __forceinline__ bf16x4 cvt4(float4 v) {
    bf16x4 b; b[0] = (bf16)v.x; b[1] = (bf16)v.y; b[2] = (bf16)v.z; b[3] = (bf16)v.w;
    return b;
}

// One LSTM cell: gates = A1@W1^T + A2@W2^T + (b1+b2); fused i,f,g,o epilogue.
// fp32 global storage, bf16 MFMA compute (fp32 accumulate).
// Gate-interleaved tile-col map: tile col t -> gate=(t>>4)&3, j = jblk+(t&15)+((t>>6)<<4),
// weight row = gate*256 + j. Then per-lane acc[mi][ni][reg]: ni == gate at fixed j.
__global__ __launch_bounds__(256, 2) void lstm_cell_kernel(
    const float* __restrict__ A1, const float* __restrict__ A2,
    const float* __restrict__ W1, const float* __restrict__ W2,
    const float* __restrict__ b1, const float* __restrict__ b2,
    const float* __restrict__ Cin,
    float* __restrict__ Hout, float* __restrict__ Cout)
{
    __shared__ __align__(16) bf16 As[BM * BK];
    __shared__ __align__(16) bf16 Bs[BM * BK];

    const int tid  = threadIdx.x;
    const int lane = tid & 63;
    const int wave = tid >> 6;
    const int wm   = wave >> 1;          // row half
    const int wn   = wave & 1;           // col half
    const int quad = lane >> 4;
    const int l15  = lane & 15;
    const int row0 = blockIdx.x * BM;
    const int jblk = blockIdx.y * 32;

    f32x4 acc[4][4];
#pragma unroll
    for (int i = 0; i < 4; ++i)
#pragma unroll
        for (int jj = 0; jj < 4; ++jj)
#pragma unroll
            for (int r = 0; r < 4; ++r) acc[i][jj][r] = 0.0f;

    for (int kIter = 0; kIter < 8; ++kIter) {
        const float* aSrc; const float* wSrc; int k0;
        if (kIter < 4) { aSrc = A1; wSrc = W1; k0 = kIter * BK; }
        else           { aSrc = A2; wSrc = W2; k0 = (kIter - 4) * BK; }

        __syncthreads();
#pragma unroll
        for (int it = 0; it < 8; ++it) {
            int c = it * 256 + tid;          // 2048 float4-chunks per tile
            int r = c >> 4;                  // tile row / tile col t (0..127)
            int kc = c & 15;                 // float4 chunk along K (0..15)
            float4 va = *(const float4*)(aSrc + (size_t)(row0 + r) * 256 + k0 + kc * 4);
            *(bf16x4*)&As[r * BK + kc * 4] = cvt4(va);
            int gate = (r >> 4) & 3;
            int j    = jblk + (r & 15) + ((r >> 6) << 4);
            float4 vb = *(const float4*)(wSrc + (size_t)(gate * 256 + j) * 256 + k0 + kc * 4);
            *(bf16x4*)&Bs[r * BK + kc * 4] = cvt4(vb);
        }
        __syncthreads();

#pragma unroll
        for (int kk = 0; kk < BK; kk += 32) {
            bf16x8 af[4], bfr[4];
#pragma unroll
            for (int mi = 0; mi < 4; ++mi)
                af[mi] = *(const bf16x8*)&As[(wm * 64 + mi * 16 + l15) * BK + kk + quad * 8];
#pragma unroll
            for (int ni = 0; ni < 4; ++ni)
                bfr[ni] = *(const bf16x8*)&Bs[(wn * 64 + ni * 16 + l15) * BK + kk + quad * 8];
#pragma unroll
            for (int mi = 0; mi < 4; ++mi)
#pragma unroll
                for (int ni = 0; ni < 4; ++ni)
                    acc[mi][ni] = __builtin_amdgcn_mfma_f32_16x16x32_bf16(
                        af[mi], bfr[ni], acc[mi][ni], 0, 0, 0);
        }
    }

    // Epilogue: acc[mi][gate][reg] at row = row0+wm*64+mi*16+quad*4+reg, col j.
    const int j = jblk + wn * 16 + l15;
    float bsum[4];
#pragma unroll
    for (int g = 0; g < 4; ++g)
        bsum[g] = b1[g * 256 + j] + b2[g * 256 + j];

#pragma unroll
    for (int mi = 0; mi < 4; ++mi) {
#pragma unroll
        for (int reg = 0; reg < 4; ++reg) {
            int row = row0 + wm * 64 + mi * 16 + quad * 4 + reg;
            float gi = acc[mi][0][reg] + bsum[0];
            float gf = acc[mi][1][reg] + bsum[1];
            float gg = acc[mi][2][reg] + bsum[2];
            float go = acc[mi][3][reg] + bsum[3];
            float c  = Cin[(size_t)row * 256 + j];
            float cn = sigmoidf_(gf) * c + sigmoidf_(gi) * tanhf_(gg);
            float hn = sigmoidf_(go) * tanhf_(cn);
            Hout[(size_t)row * 256 + j] = hn;
            Cout[(size_t)row * 256 + j] = cn;
        }
    }
}

// Out[B,256] = A[B,256] @ W[256,256]^T + bias   (fp32 storage, bf16 MFMA)
__global__ __launch_bounds__(256, 2) void linear_kernel(
    const float* __restrict__ A, const float* __restrict__ W,
    const float* __restrict__ bias, float* __restrict__ Out)
{
    __shared__ __align__(16) bf16 As[BM * BK];
    __shared__ __align__(16) bf16 Bs[BM * BK];

    const int tid  = threadIdx.x;
    const int lane = tid & 63;
    const int wave = tid >> 6;
    const int wm   = wave >> 1;
    const int wn   = wave & 1;
    const int quad = lane >> 4;
    const int l15  = lane & 15;
    const int row0 = blockIdx.x * BM;
    const int n0   = blockIdx.y * 128;

    f32x4 acc[4][4];
#pragma unroll
    for (int i = 0; i < 4; ++i)
#pragma unroll
        for (int jj = 0; jj < 4; ++jj)
#pragma unroll
            for (int r = 0; r < 4; ++r) acc[i][jj][r] = 0.0f;

    for (int kIter = 0; kIter < 4; ++kIter) {
        int k0 = kIter * BK;
        __syncthreads();
#pragma unroll
        for (int it = 0; it < 8; ++it) {
            int c = it * 256 + tid;
            int r = c >> 4, kc = c & 15;
            float4 va = *(const float4*)(A + (size_t)(row0 + r) * 256 + k0 + kc * 4);
            *(bf16x4*)&As[r * BK + kc * 4] = cvt4(va);
            float4 vb = *(const float4*)(W + (size_t)(n0 + r) * 256 + k0 + kc * 4);
            *(bf16x4*)&Bs[r * BK + kc * 4] = cvt4(vb);
        }
        __syncthreads();

#pragma unroll
        for (int kk = 0; kk < BK; kk += 32) {
            bf16x8 af[4], bfr[4];
#pragma unroll
            for (int mi = 0; mi < 4; ++mi)
                af[mi] = *(const bf16x8*)&As[(wm * 64 + mi * 16 + l15) * BK + kk + quad * 8];
#pragma unroll
            for (int ni = 0; ni < 4; ++ni)
                bfr[ni] = *(const bf16x8*)&Bs[(wn * 64 + ni * 16 + l15) * BK + kk + quad * 8];
#pragma unroll
            for (int mi = 0; mi < 4; ++mi)
#pragma unroll
                for (int ni = 0; ni < 4; ++ni)
                    acc[mi][ni] = __builtin_amdgcn_mfma_f32_16x16x32_bf16(
                        af[mi], bfr[ni], acc[mi][ni], 0, 0, 0);
        }
    }

#pragma unroll
    for (int mi = 0; mi < 4; ++mi) {
#pragma unroll
        for (int ni = 0; ni < 4; ++ni) {
            int n = n0 + wn * 64 + ni * 16 + l15;
            float bv = bias[n];
#pragma unroll
            for (int reg = 0; reg < 4; ++reg) {
                int row = row0 + wm * 64 + mi * 16 + quad * 4 + reg;
                Out[(size_t)row * 256 + n] = acc[mi][ni][reg] + bv;
            }
        }
    }
}

extern "C" void kernel_launch(void* const* d_in, const int* in_sizes, int n_in,
                              void* d_out, int out_size, void* d_ws, size_t ws_size,
                              hipStream_t stream) {
    const float* x     = (const float*)d_in[0];
    const float* h_all = (const float*)d_in[1];
    const float* c_all = (const float*)d_in[2];
    const float* Wih0  = (const float*)d_in[3];
    const float* Whh0  = (const float*)d_in[4];
    const float* bih0  = (const float*)d_in[5];
    const float* bhh0  = (const float*)d_in[6];
    const float* Wih   = (const float*)d_in[7];
    const float* Whh   = (const float*)d_in[8];
    const float* bih   = (const float*)d_in[9];
    const float* bhh   = (const float*)d_in[10];
    const float* Wout  = (const float*)d_in[11];
    const float* bout  = (const float*)d_in[12];
    float* out = (float*)d_out;

    float* hs = out + SL;        // hs[l] = hs + l*SL, l = 0..7
    float* cs = out + SL * 9;    // cs[l] = cs + l*SL

    dim3 grid(BROWS / BM, 8), block(256);

    // cell 0 (input cell)
    lstm_cell_kernel<<<grid, block, 0, stream>>>(
        x, h_all, Wih0, Whh0, bih0, bhh0, c_all, hs, cs);

    // cells 1..7 — sequential layer recurrence
    for (int l = 1; l <= 7; ++l) {
        lstm_cell_kernel<<<grid, block, 0, stream>>>(
            hs + (size_t)(l - 1) * SL,
            h_all + (size_t)l * SL,
            Wih + (size_t)(l - 1) * 1024 * 256,
            Whh + (size_t)(l - 1) * 1024 * 256,
            bih + (size_t)(l - 1) * 1024,
            bhh + (size_t)(l - 1) * 1024,
            c_all + (size_t)l * SL,
            hs + (size_t)l * SL,
            cs + (size_t)l * SL);
    }

    // output linear on hs[7]
    linear_kernel<<<dim3(BROWS / BM, 2), block, 0, stream>>>(
        hs + SL * 7, Wout, bout, out);
}